// Round 5
// baseline (1350.251 us; speedup 1.0000x reference)
//
#include <hip/hip_runtime.h>
#include <math.h>

typedef unsigned short u16;
typedef unsigned int u32;
typedef short short8 __attribute__((ext_vector_type(8)));
typedef float f32x4 __attribute__((ext_vector_type(4)));
typedef unsigned int u32x2 __attribute__((ext_vector_type(2)));

#define SCALE_QK 0.17677669529663687f  // 32^-0.5
#define PSLAB 23296                    // P slab per batch (u16): [8][52][56], lives in d_out

__device__ __forceinline__ float b2f(u16 v) { return __uint_as_float(((u32)v) << 16); }
__device__ __forceinline__ u16 f2b(float f) {
  u32 u = __float_as_uint(f);
  return (u16)((u + 0x7fffu + ((u >> 16) & 1u)) >> 16);
}

// Branchless GELU via A&S 7.1.26 erf (|eps| <= 1.5e-7): ~15 VALU, no divergence.
__device__ __forceinline__ float gelu_f(float z) {
  float y = z * 0.70710678118654752f;
  float a = fabsf(y);
  float t = __builtin_amdgcn_rcpf(fmaf(0.3275911f, a, 1.0f));
  float e = __expf(-y * y);
  float p = fmaf(1.061405429f, t, -1.453152027f);
  p = fmaf(p, t, 1.421413741f);
  p = fmaf(p, t, -0.284496736f);
  p = fmaf(p, t, 0.254829592f);
  p = p * t * e;                         // erfc(a) approx
  float phi = (y >= 0.f) ? fmaf(-0.5f, p, 1.0f) : 0.5f * p;
  return z * phi;
}

// ---- K0: fold BN params, premix bias through th1, convert weights to bf16 ----
__global__ __launch_bounds__(256) void k_pre(
    const float* __restrict__ th1w, const float* __restrict__ th1b, const float* __restrict__ ab,
    const float* __restrict__ qb, const float* __restrict__ qs, const float* __restrict__ qo,
    const float* __restrict__ kb, const float* __restrict__ ks, const float* __restrict__ ko,
    const float* __restrict__ vb, const float* __restrict__ vs, const float* __restrict__ vo,
    const float* __restrict__ pb, const float* __restrict__ ps, const float* __restrict__ po,
    const float* __restrict__ qw, const float* __restrict__ kw,
    const float* __restrict__ vw, const float* __restrict__ pw,
    float* __restrict__ bias2, float* __restrict__ alpha, float* __restrict__ beta,
    float* __restrict__ alphap, float* __restrict__ betap,
    u16* __restrict__ Wqk, u16* __restrict__ Wv, u16* __restrict__ Wp)
{
  int gid = blockIdx.x * 256 + threadIdx.x;
  if (gid < 19208) {
    int i = gid / 2401, rem = gid % 2401, n = rem / 49, m = rem % 49;
    int ry = abs(n / 7 - m / 7), rx = abs(n % 7 - m % 7);
    int idx = ry * 7 + rx;
    float acc = th1b[i];
    #pragma unroll
    for (int j = 0; j < 8; j++) acc += th1w[i * 8 + j] * ab[j * 49 + idx];
    bias2[gid] = acc;
  } else if (gid < 20744) {
    int c = gid - 19208;
    const float *s, *bb, *oo; int idx;
    if (c < 256)      { s = qs; bb = qb; oo = qo; idx = c; }
    else if (c < 512) { s = ks; bb = kb; oo = ko; idx = c - 256; }
    else              { s = vs; bb = vb; oo = vo; idx = c - 512; }
    float sv = s[idx];
    alpha[c] = sv;
    beta[c] = sv * bb[idx] + oo[idx];
  } else if (gid < 21128) {
    int c = gid - 20744;
    float sv = ps[c];
    alphap[c] = sv;
    betap[c] = sv * pb[c] + po[c];
  } else {
    int g = gid - 21128;
    if (g < 98304)       Wqk[g] = f2b(qw[g]);                 // q rows 0..255
    else if (g < 196608) Wqk[g] = f2b(kw[g - 98304]);         // k rows 256..511
    else if (g < 589824) Wv[g - 196608] = f2b(vw[g - 196608]);
    else if (g < 983040) Wp[g - 589824] = f2b(pw[g - 589824]);
  }
}

// ---- K1: per batch q/k GEMM + QK^T -> raw scaled scores into P (in d_out) ----
// Also exports the staged XT tile (bf16, [64][384], zero rows 49..63) to XTg
// when XTg != nullptr, so downstream kernels stage it back with no arithmetic.
__global__ __launch_bounds__(512, 4) void k_qk(
    const float* __restrict__ x, const u16* __restrict__ Wqk,
    const float* __restrict__ alpha, const float* __restrict__ beta,
    u16* __restrict__ Pbuf, u16* __restrict__ XTg)
{
  __shared__ __align__(16) u16 lds[37376];   // 74752 B -> 2 blocks/CU
  u16* XT = lds;               // [64][408]  (stride 816B: 16B-aligned, ~2-way banks)
  u16* Tq = lds + 26112;       // [64][88]
  u16* Tk = lds + 31744;       // [64][88]
  int t = threadIdx.x, wv = t >> 6, l = t & 63, quad = l >> 4, l16 = l & 15;
  int b = blockIdx.x;
  const float* xb = x + (size_t)b * 18816;

  for (int e = t; e < 18816; e += 512) {
    int k = e / 49, n = e - k * 49;
    XT[n * 408 + k] = f2b(xb[e]);
  }
  for (int e = t; e < 3060; e += 512) {  // zero rows 49..63 (must be finite!)
    int r = e / 204, kk = e - r * 204;
    ((u32*)(XT + (49 + r) * 408))[kk] = 0;
  }
  __syncthreads();

  if (XTg) {  // export XT (cols 0..383 only) to global; drains in background
    u32* dst = (u32*)(XTg + (size_t)b * 24576);
    const u32* src32 = (const u32*)XT;
    for (int e = t; e < 12288; e += 512) {
      int row = e / 192, cc = e - row * 192;
      dst[e] = src32[row * 204 + cc];
    }
  }

  u16* Pg = Pbuf + (size_t)b * PSLAB;   // [8][52][56]
  int isK = wv >= 4, wl = wv & 3;
  for (int hp = 0; hp < 4; hp++) {
    int cbase = (isK ? 256 : 0) + hp * 64 + wl * 16;
    f32x4 acc[4] = {};
    const u16* Wr = Wqk + (size_t)(cbase + l16) * 384;
    short8 afr[12];                        // preload A frags: one latency, not 12
    #pragma unroll
    for (int ks = 0; ks < 12; ks++) afr[ks] = *(const short8*)(Wr + ks * 32 + quad * 8);
    #pragma unroll
    for (int ks = 0; ks < 12; ks++) {
      #pragma unroll
      for (int nt = 0; nt < 4; nt++) {
        short8 bf = *(const short8*)(&XT[(nt * 16 + l16) * 408 + ks * 32 + quad * 8]);
        acc[nt] = __builtin_amdgcn_mfma_f32_16x16x32_bf16(afr[ks], bf, acc[nt], 0, 0, 0);
      }
    }
    u16* Tdst = isK ? Tk : Tq;
    #pragma unroll
    for (int reg = 0; reg < 4; reg++) {
      int c = cbase + quad * 4 + reg;
      float al = alpha[c], be = beta[c];
      int cl = wl * 16 + quad * 4 + reg;
      #pragma unroll
      for (int nt = 0; nt < 4; nt++)
        Tdst[(nt * 16 + l16) * 88 + cl] = f2b(acc[nt][reg] * al + be);
    }
    __syncthreads();
    #pragma unroll
    for (int ui = 0; ui < 4; ui++) {
      int u = wv * 4 + ui;                    // 32 tiles: 2 heads x 4x4
      int hl = u >> 4, tn = (u >> 2) & 3, tm = u & 3;
      short8 a  = *(const short8*)(&Tq[(tn * 16 + l16) * 88 + hl * 32 + quad * 8]);
      short8 bb = *(const short8*)(&Tk[(tm * 16 + l16) * 88 + hl * 32 + quad * 8]);
      f32x4 c = {};
      c = __builtin_amdgcn_mfma_f32_16x16x32_bf16(a, bb, c, 0, 0, 0);
      int h = hp * 2 + hl;
      #pragma unroll
      for (int r = 0; r < 4; r++) {
        int n = tn * 16 + quad * 4 + r, m = tm * 16 + l16;
        // write full padded slab: pads = 0 (d_out is poisoned; no NaN may survive)
        if (n < 52 && m < 56)
          Pg[(h * 52 + n) * 56 + m] = (n < 49 && m < 49) ? f2b(c[r] * SCALE_QK) : (u16)0;
      }
    }
    __syncthreads();
  }
}

// ---- K2: mix1 + bias, softmax, mix2 — in place on P ----
__global__ __launch_bounds__(256, 4) void k_mix(
    u16* __restrict__ Pbuf, const float* __restrict__ bias2,
    const float* __restrict__ th1w, const float* __restrict__ th1b,
    const float* __restrict__ th2w, const float* __restrict__ th2b)
{
  __shared__ u16 SB[23296];    // [8][52][56]
  __shared__ float TH[144];
  int t = threadIdx.x, b = blockIdx.x;
  u32* Pg32 = (u32*)(Pbuf + (size_t)b * PSLAB);
  for (int e = t; e < 11648; e += 256) ((u32*)SB)[e] = Pg32[e];
  if (t < 64)       TH[t] = th1w[t];
  else if (t < 72)  TH[t] = th1b[t - 64];
  else if (t < 136) TH[t] = th2w[t - 72];
  else if (t < 144) TH[t] = th2b[t - 136];
  __syncthreads();
  for (int e = t; e < 2401; e += 256) {
    int n = e / 49, m = e - n * 49;
    float s[8], uo[8];
    #pragma unroll
    for (int j = 0; j < 8; j++) s[j] = b2f(SB[(j * 52 + n) * 56 + m]);
    #pragma unroll
    for (int i = 0; i < 8; i++) {
      float a2 = bias2[(i * 49 + n) * 49 + m];
      #pragma unroll
      for (int j = 0; j < 8; j++) a2 += TH[i * 8 + j] * s[j];
      uo[i] = a2;
    }
    #pragma unroll
    for (int i = 0; i < 8; i++) SB[(i * 52 + n) * 56 + m] = f2b(uo[i]);
  }
  __syncthreads();
  for (int r0 = t; r0 < 392; r0 += 256) {
    int i = r0 / 49, n = r0 - i * 49;
    u16* row = &SB[(i * 52 + n) * 56];
    float v[49]; float mx = -1e30f;
    #pragma unroll
    for (int m = 0; m < 49; m++) { v[m] = b2f(row[m]); mx = fmaxf(mx, v[m]); }
    float sum = 0.f;
    #pragma unroll
    for (int m = 0; m < 49; m++) { v[m] = __expf(v[m] - mx); sum += v[m]; }
    float inv = 1.f / sum;
    #pragma unroll
    for (int m = 0; m < 49; m++) row[m] = f2b(v[m] * inv);
  }
  __syncthreads();
  for (int e = t; e < 2401; e += 256) {
    int n = e / 49, m = e - n * 49;
    float s[8], uo[8];
    #pragma unroll
    for (int j = 0; j < 8; j++) s[j] = b2f(SB[(j * 52 + n) * 56 + m]);
    #pragma unroll
    for (int i = 0; i < 8; i++) {
      float a2 = TH[136 + i];
      #pragma unroll
      for (int j = 0; j < 8; j++) a2 += TH[72 + i * 8 + j] * s[j];
      uo[i] = a2;
    }
    #pragma unroll
    for (int i = 0; i < 8; i++) SB[(i * 52 + n) * 56 + m] = f2b(uo[i]);
  }
  __syncthreads();
  for (int e = t; e < 11648; e += 256) Pg32[e] = ((u32*)SB)[e];
}

// ---- K3a (huge-ws): v GEMM only. XT in LDS (52KB -> 3 blocks/CU), zero
// per-head barriers; BN-folded bf16 V written to Vg[b][1024][56]
// (cols 49..55 zero). Pure MFMA streaming.
__global__ __launch_bounds__(512, 6) void k_vg(
    const u16* __restrict__ XTg, const u16* __restrict__ Wv,
    const float* __restrict__ alpha, const float* __restrict__ beta,
    u16* __restrict__ Vg)
{
  __shared__ __align__(16) u16 XT[26112];   // [64][408]
  int t = threadIdx.x, wv = t >> 6, l = t & 63, quad = l >> 4, l16 = l & 15;
  int b = blockIdx.x;

  { // XT import: chunks of 8 u16; row stride 408 u16 = 816 B (16B-aligned)
    const short8* src8 = (const short8*)(XTg + (size_t)b * 24576);
    for (int e = t; e < 3072; e += 512) {
      int row = e / 48, cc = e - row * 48;
      *(short8*)(XT + row * 408 + cc * 8) = src8[e];
    }
  }
  __syncthreads();

  u16* Vb = Vg + (size_t)b * 57344;          // [1024][56]
  for (int h = 0; h < 8; h++) {
    const u16* Wr = Wv + (size_t)(h * 128 + wv * 16 + l16) * 384;
    short8 afr[12];
    #pragma unroll
    for (int ks = 0; ks < 12; ks++) afr[ks] = *(const short8*)(Wr + ks * 32 + quad * 8);
    f32x4 va[4] = {};
    #pragma unroll
    for (int ks = 0; ks < 12; ks++) {
      #pragma unroll
      for (int nt = 0; nt < 4; nt++) {
        short8 bf = *(const short8*)(&XT[(nt * 16 + l16) * 408 + ks * 32 + quad * 8]);
        va[nt] = __builtin_amdgcn_mfma_f32_16x16x32_bf16(afr[ks], bf, va[nt], 0, 0, 0);
      }
    }
    #pragma unroll
    for (int reg = 0; reg < 4; reg++) {
      int c = h * 128 + wv * 16 + quad * 4 + reg;
      float al = alpha[512 + c], be = beta[512 + c];
      #pragma unroll
      for (int nt = 0; nt < 4; nt++) {
        int m = nt * 16 + l16;
        if (m < 49)      Vb[(size_t)c * 56 + m] = f2b(va[nt][reg] * al + be);
        else if (m < 56) Vb[(size_t)c * 56 + m] = 0;   // pad cols stay zero
      }
    }
  }
}

// ---- K3b (huge-ws): PV + dwconv + GELU. LDS = VT+Ph = 25.7KB ->
// 4 blocks/CU (100% occupancy). V-tile staged per head with 2 vector
// loads/thread; epilogue VALU overlaps across 32 waves.
__global__ __launch_bounds__(512, 8) void k_pv(
    const u16* __restrict__ Vg,
    const float* __restrict__ vlw, const float* __restrict__ vlb,
    const float* __restrict__ vls, const float* __restrict__ vlo,
    const u16* __restrict__ Pbuf, u16* __restrict__ Zs)
{
  __shared__ __align__(16) u16 lds[12856];   // VT[128][72]=9216 + Ph[65][56]=3640
  u16* VT = lds;               // data at col 8+m; cols 0..7 and 64..71 stay zero
  u16* Ph = lds + 9216;
  int t = threadIdx.x, wv = t >> 6, l = t & 63, quad = l >> 4, l16 = l & 15;
  int b = blockIdx.x;
  int d = wv * 16 + l16;

  // zero VT pad cols (0..7, 64..71) once; persists across heads
  for (int e = t; e < 1024; e += 512) {
    int row = e >> 3, k = e & 7;
    int col = k < 4 ? k * 2 : 64 + (k - 4) * 2;
    *(u32*)(&VT[row * 72 + col]) = 0;
  }

  u16* Zb = Zs + (size_t)b * 50176;          // Zt: [49][1024], n-major
  const u16* Pgb = Pbuf + (size_t)b * PSLAB;
  const u16* Vb = Vg + (size_t)b * 57344;
  for (int h = 0; h < 8; h++) {
    { // stage V tile: 128 rows x 56 u16 from Vg -> VT cols 8..63
      const short8* src = (const short8*)(Vb + (size_t)h * 128 * 56);
      for (int e = t; e < 896; e += 512) {
        int row = e / 7, cc = e - row * 7;
        *(short8*)(&VT[row * 72 + 8 + cc * 8]) = src[e];
      }
    }
    { // P tile copy
      const u32* src = (const u32*)(Pgb + h * 2912);
      for (int e = t; e < 1456; e += 512) ((u32*)Ph)[e] = src[e];
    }
    __syncthreads();

    int c = h * 128 + d;
    float w9[9];
    #pragma unroll
    for (int j = 0; j < 9; j++) w9[j] = vlw[c * 9 + j];
    float sv = vls[c];
    float cb = sv * vlb[c] + vlo[c];

    f32x4 oa[4] = {};
    #pragma unroll
    for (int ks2 = 0; ks2 < 2; ks2++) {
      int mb = ks2 * 32 + quad * 8;
      short8 bf = *(const short8*)(&VT[(wv * 16 + l16) * 72 + 8 + mb]);
      #pragma unroll
      for (int tn = 0; tn < 4; tn++) {
        short8 af = *(const short8*)(&Ph[(tn * 16 + l16) * 56 + mb]);
        oa[tn] = __builtin_amdgcn_mfma_f32_16x16x32_bf16(af, bf, oa[tn], 0, 0, 0);
      }
    }
    const u16* vtr = &VT[d * 72];
    #pragma unroll
    for (int tn = 0; tn < 4; tn++) {
      int n0 = tn * 16 + quad * 4;
      const u16* vr = vtr + n0;      // col(n0+j) holds spatial m = n0+j-8
      float q[20];
      #pragma unroll
      for (int jj = 0; jj < 5; jj++) {
        u32x2 U = *(const u32x2*)(vr + jj * 4);
        q[jj * 4 + 0] = __uint_as_float(U.x << 16);
        q[jj * 4 + 1] = __uint_as_float(U.x & 0xffff0000u);
        q[jj * 4 + 2] = __uint_as_float(U.y << 16);
        q[jj * 4 + 3] = __uint_as_float(U.y & 0xffff0000u);
      }
      #pragma unroll
      for (int r = 0; r < 4; r++) {
        int n = n0 + r;
        int yi = (n * 37) >> 8;        // == n/7 for n < 64
        int xi = n - yi * 7;
        bool xl = xi > 0, xr = xi < 6;
        float w0m = xl ? w9[0] : 0.f, w3m = xl ? w9[3] : 0.f, w6m = xl ? w9[6] : 0.f;
        float w2m = xr ? w9[2] : 0.f, w5m = xr ? w9[5] : 0.f, w8m = xr ? w9[8] : 0.f;
        float conv = q[r]      * w0m + q[r + 1]  * w9[1] + q[r + 2]  * w2m
                   + q[r + 7]  * w3m + q[r + 8]  * w9[4] + q[r + 9]  * w5m
                   + q[r + 14] * w6m + q[r + 15] * w9[7] + q[r + 16] * w8m;
        float z = oa[tn][r] + conv * sv + cb;
        float g = gelu_f(z);
        if (n < 49) Zb[(size_t)n * 1024 + c] = f2b(g);   // transposed store
      }
    }
    __syncthreads();
  }
}

// ---- K3 (big-ws fallback): round-4 monolithic k_av with XT import ----
__global__ __launch_bounds__(512, 4) void k_av_x(
    const u16* __restrict__ XTg, const u16* __restrict__ Wv,
    const float* __restrict__ alpha, const float* __restrict__ beta,
    const float* __restrict__ vlw, const float* __restrict__ vlb,
    const float* __restrict__ vls, const float* __restrict__ vlo,
    const u16* __restrict__ Pbuf, u16* __restrict__ Zs)
{
  __shared__ __align__(16) u16 lds[38968];   // 77936 B -> 2 blocks/CU
  u16* XT = lds;               // [64][408]
  u16* VT = lds + 26112;       // [128][72]
  u16* Ph = lds + 35328;       // [65][56]
  int t = threadIdx.x, wv = t >> 6, l = t & 63, quad = l >> 4, l16 = l & 15;
  int b = blockIdx.x;

  {
    const short8* src8 = (const short8*)(XTg + (size_t)b * 24576);
    for (int e = t; e < 3072; e += 512) {
      int row = e / 48, cc = e - row * 48;
      *(short8*)(XT + row * 408 + cc * 8) = src8[e];
    }
  }
  for (int e = t; e < 4608; e += 512) ((u32*)VT)[e] = 0;
  __syncthreads();

  u16* Zb = Zs + (size_t)b * 50176;
  const u16* Pgb = Pbuf + (size_t)b * PSLAB;
  for (int h = 0; h < 8; h++) {
    {
      const u32* src = (const u32*)(Pgb + h * 2912);
      for (int e = t; e < 1456; e += 512) ((u32*)Ph)[e] = src[e];
    }
    const u16* Wr = Wv + (size_t)(h * 128 + wv * 16 + l16) * 384;
    short8 afr[12];
    #pragma unroll
    for (int ks = 0; ks < 12; ks++) afr[ks] = *(const short8*)(Wr + ks * 32 + quad * 8);
    int d = wv * 16 + l16, c = h * 128 + d;
    float w9[9];
    #pragma unroll
    for (int j = 0; j < 9; j++) w9[j] = vlw[c * 9 + j];
    float sv = vls[c];
    float cb = sv * vlb[c] + vlo[c];

    f32x4 va[4] = {};
    #pragma unroll
    for (int ks = 0; ks < 12; ks++) {
      #pragma unroll
      for (int nt = 0; nt < 4; nt++) {
        short8 bf = *(const short8*)(&XT[(nt * 16 + l16) * 408 + ks * 32 + quad * 8]);
        va[nt] = __builtin_amdgcn_mfma_f32_16x16x32_bf16(afr[ks], bf, va[nt], 0, 0, 0);
      }
    }
    #pragma unroll
    for (int reg = 0; reg < 4; reg++) {
      int dl = wv * 16 + quad * 4 + reg;
      int cc = h * 128 + dl;
      float al = alpha[512 + cc], be = beta[512 + cc];
      #pragma unroll
      for (int nt = 0; nt < 4; nt++) {
        int m = nt * 16 + l16;
        if (m < 49) VT[dl * 72 + 8 + m] = f2b(va[nt][reg] * al + be);
      }
    }
    __syncthreads();
    f32x4 oa[4] = {};
    #pragma unroll
    for (int ks2 = 0; ks2 < 2; ks2++) {
      int mb = ks2 * 32 + quad * 8;
      short8 bf = *(const short8*)(&VT[(wv * 16 + l16) * 72 + 8 + mb]);
      #pragma unroll
      for (int tn = 0; tn < 4; tn++) {
        short8 af = *(const short8*)(&Ph[(tn * 16 + l16) * 56 + mb]);
        oa[tn] = __builtin_amdgcn_mfma_f32_16x16x32_bf16(af, bf, oa[tn], 0, 0, 0);
      }
    }
    const u16* vtr = &VT[d * 72];
    #pragma unroll
    for (int tn = 0; tn < 4; tn++) {
      int n0 = tn * 16 + quad * 4;
      const u16* vr = vtr + n0;
      float q[20];
      #pragma unroll
      for (int jj = 0; jj < 5; jj++) {
        u32x2 U = *(const u32x2*)(vr + jj * 4);
        q[jj * 4 + 0] = __uint_as_float(U.x << 16);
        q[jj * 4 + 1] = __uint_as_float(U.x & 0xffff0000u);
        q[jj * 4 + 2] = __uint_as_float(U.y << 16);
        q[jj * 4 + 3] = __uint_as_float(U.y & 0xffff0000u);
      }
      #pragma unroll
      for (int r = 0; r < 4; r++) {
        int n = n0 + r;
        int yi = (n * 37) >> 8;
        int xi = n - yi * 7;
        bool xl = xi > 0, xr = xi < 6;
        float w0m = xl ? w9[0] : 0.f, w3m = xl ? w9[3] : 0.f, w6m = xl ? w9[6] : 0.f;
        float w2m = xr ? w9[2] : 0.f, w5m = xr ? w9[5] : 0.f, w8m = xr ? w9[8] : 0.f;
        float conv = q[r]      * w0m + q[r + 1]  * w9[1] + q[r + 2]  * w2m
                   + q[r + 7]  * w3m + q[r + 8]  * w9[4] + q[r + 9]  * w5m
                   + q[r + 14] * w6m + q[r + 15] * w9[7] + q[r + 16] * w8m;
        float z = oa[tn][r] + conv * sv + cb;
        float g = gelu_f(z);
        if (n < 49) Zb[(size_t)n * 1024 + c] = f2b(g);
      }
    }
    __syncthreads();
  }
}

// ---- K3 (small-ws fallback): round-2 k_av, stages from x directly ----
__global__ __launch_bounds__(512, 4) void k_av_fb(
    const float* __restrict__ x, const u16* __restrict__ Wv,
    const float* __restrict__ alpha, const float* __restrict__ beta,
    const float* __restrict__ vlw, const float* __restrict__ vlb,
    const float* __restrict__ vls, const float* __restrict__ vlo,
    const u16* __restrict__ Pbuf, u16* __restrict__ Zs)
{
  __shared__ __align__(16) u16 lds[38968];
  u16* XT = lds;               // [64][408]
  u16* VT = lds + 26112;       // [128][72]
  u16* Ph = lds + 35328;       // [65][56]
  int t = threadIdx.x, wv = t >> 6, l = t & 63, quad = l >> 4, l16 = l & 15;
  int b = blockIdx.x;
  const float* xb = x + (size_t)b * 18816;

  for (int e = t; e < 18816; e += 512) {
    int k = e / 49, n = e - k * 49;
    XT[n * 408 + k] = f2b(xb[e]);
  }
  for (int e = t; e < 3060; e += 512) {
    int r = e / 204, kk = e - r * 204;
    ((u32*)(XT + (49 + r) * 408))[kk] = 0;
  }
  for (int e = t; e < 4608; e += 512) ((u32*)VT)[e] = 0;
  __syncthreads();

  u16* Zb = Zs + (size_t)b * 50176;
  const u16* Pgb = Pbuf + (size_t)b * PSLAB;
  for (int h = 0; h < 8; h++) {
    {
      const u32* src = (const u32*)(Pgb + h * 2912);
      for (int e = t; e < 1456; e += 512) ((u32*)Ph)[e] = src[e];
    }
    const u16* Wr = Wv + (size_t)(h * 128 + wv * 16 + l16) * 384;
    short8 afr[12];
    #pragma unroll
    for (int ks = 0; ks < 12; ks++) afr[ks] = *(const short8*)(Wr + ks * 32 + quad * 8);
    int d = wv * 16 + l16, c = h * 128 + d;
    float w9[9];
    #pragma unroll
    for (int j = 0; j < 9; j++) w9[j] = vlw[c * 9 + j];
    float sv = vls[c];
    float cb = sv * vlb[c] + vlo[c];

    f32x4 va[4] = {};
    #pragma unroll
    for (int ks = 0; ks < 12; ks++) {
      #pragma unroll
      for (int nt = 0; nt < 4; nt++) {
        short8 bf = *(const short8*)(&XT[(nt * 16 + l16) * 408 + ks * 32 + quad * 8]);
        va[nt] = __builtin_amdgcn_mfma_f32_16x16x32_bf16(afr[ks], bf, va[nt], 0, 0, 0);
      }
    }
    #pragma unroll
    for (int reg = 0; reg < 4; reg++) {
      int dl = wv * 16 + quad * 4 + reg;
      int cc = h * 128 + dl;
      float al = alpha[512 + cc], be = beta[512 + cc];
      #pragma unroll
      for (int nt = 0; nt < 4; nt++) {
        int m = nt * 16 + l16;
        if (m < 49) VT[dl * 72 + 8 + m] = f2b(va[nt][reg] * al + be);
      }
    }
    __syncthreads();
    f32x4 oa[4] = {};
    #pragma unroll
    for (int ks2 = 0; ks2 < 2; ks2++) {
      int mb = ks2 * 32 + quad * 8;
      short8 bf = *(const short8*)(&VT[(wv * 16 + l16) * 72 + 8 + mb]);
      #pragma unroll
      for (int tn = 0; tn < 4; tn++) {
        short8 af = *(const short8*)(&Ph[(tn * 16 + l16) * 56 + mb]);
        oa[tn] = __builtin_amdgcn_mfma_f32_16x16x32_bf16(af, bf, oa[tn], 0, 0, 0);
      }
    }
    const u16* vtr = &VT[d * 72];
    #pragma unroll
    for (int tn = 0; tn < 4; tn++) {
      int n0 = tn * 16 + quad * 4;
      const u16* vr = vtr + n0;
      float q[20];
      #pragma unroll
      for (int jj = 0; jj < 5; jj++) {
        u32x2 U = *(const u32x2*)(vr + jj * 4);
        q[jj * 4 + 0] = __uint_as_float(U.x << 16);
        q[jj * 4 + 1] = __uint_as_float(U.x & 0xffff0000u);
        q[jj * 4 + 2] = __uint_as_float(U.y << 16);
        q[jj * 4 + 3] = __uint_as_float(U.y & 0xffff0000u);
      }
      #pragma unroll
      for (int r = 0; r < 4; r++) {
        int n = n0 + r;
        int yi = (n * 37) >> 8;
        int xi = n - yi * 7;
        bool xl = xi > 0, xr = xi < 6;
        float w0m = xl ? w9[0] : 0.f, w3m = xl ? w9[3] : 0.f, w6m = xl ? w9[6] : 0.f;
        float w2m = xr ? w9[2] : 0.f, w5m = xr ? w9[5] : 0.f, w8m = xr ? w9[8] : 0.f;
        float conv = q[r]      * w0m + q[r + 1]  * w9[1] + q[r + 2]  * w2m
                   + q[r + 7]  * w3m + q[r + 8]  * w9[4] + q[r + 9]  * w5m
                   + q[r + 14] * w6m + q[r + 15] * w9[7] + q[r + 16] * w8m;
        float z = oa[tn][r] + conv * sv + cb;
        float g = gelu_f(z);
        if (n < 49) Zb[(size_t)n * 1024 + c] = f2b(g);
      }
    }
    __syncthreads();
  }
}

// ---- K4: output projection, 128x128 tiles, 2 batches/block ----
__global__ __launch_bounds__(512, 4) void k_proj(
    const u16* __restrict__ Wp, const u16* __restrict__ Zt,
    const float* __restrict__ alphap, const float* __restrict__ betap,
    float* __restrict__ out)
{
  __shared__ __align__(16) u16 Bs[128 * 152];   // 38912 B -> 4 blocks/CU
  int t = threadIdx.x, wv = t >> 6, l = t & 63, quad = l >> 4, l16 = l & 15;
  int g = blockIdx.x;
  int vb = (g & 7) * 192 + (g >> 3);
  int mb = vb % 3;
  size_t b0 = (size_t)(vb / 3) * 2;
  f32x4 acc[8] = {};
  const u16* Wr = Wp + (size_t)(mb * 128 + wv * 16 + l16) * 1024;
  for (int k0 = 0; k0 < 1024; k0 += 128) {
    #pragma unroll
    for (int i = 0; i < 4; i++) {
      int ch = t + i * 512;              // 2048 chunks of 8 u16
      int np = ch >> 4, ck = ch & 15;
      int pb = np >> 6, n = np & 63;
      short8 v = {};
      if (n < 49)
        v = *(const short8*)(Zt + (b0 + pb) * 50176 + (size_t)n * 1024 + k0 + ck * 8);
      *(short8*)(&Bs[np * 152 + ck * 8]) = v;
    }
    __syncthreads();
    #pragma unroll
    for (int ksi = 0; ksi < 4; ksi++) {
      short8 af = *(const short8*)(Wr + k0 + ksi * 32 + quad * 8);
      #pragma unroll
      for (int nt = 0; nt < 8; nt++) {
        short8 bf = *(const short8*)(&Bs[(nt * 16 + l16) * 152 + ksi * 32 + quad * 8]);
        acc[nt] = __builtin_amdgcn_mfma_f32_16x16x32_bf16(af, bf, acc[nt], 0, 0, 0);
      }
    }
    __syncthreads();
  }
  #pragma unroll
  for (int reg = 0; reg < 4; reg++) {
    int c = mb * 128 + wv * 16 + quad * 4 + reg;
    float al = alphap[c], be = betap[c];
    #pragma unroll
    for (int nt = 0; nt < 8; nt++) {
      int np = nt * 16 + l16, pb = np >> 6, n = np & 63;
      if (n < 49) out[(b0 + pb) * 18816 + (size_t)c * 49 + n] = acc[nt][reg] * al + be;
    }
  }
}

extern "C" void kernel_launch(void* const* d_in, const int* in_sizes, int n_in,
                              void* d_out, int out_size, void* d_ws, size_t ws_size,
                              hipStream_t stream) {
  const float* x    = (const float*)d_in[0];
  const float* qw   = (const float*)d_in[1];
  const float* qb   = (const float*)d_in[2];
  const float* qs   = (const float*)d_in[3];
  const float* qo   = (const float*)d_in[4];
  const float* kw   = (const float*)d_in[5];
  const float* kb   = (const float*)d_in[6];
  const float* ks   = (const float*)d_in[7];
  const float* ko   = (const float*)d_in[8];
  const float* vw   = (const float*)d_in[9];
  const float* vb   = (const float*)d_in[10];
  const float* vs   = (const float*)d_in[11];
  const float* vo   = (const float*)d_in[12];
  const float* vlw  = (const float*)d_in[13];
  const float* vlb  = (const float*)d_in[14];
  const float* vls  = (const float*)d_in[15];
  const float* vlo  = (const float*)d_in[16];
  const float* th1w = (const float*)d_in[17];
  const float* th1b = (const float*)d_in[18];
  const float* th2w = (const float*)d_in[19];
  const float* th2b = (const float*)d_in[20];
  const float* pw   = (const float*)d_in[21];
  const float* pb   = (const float*)d_in[22];
  const float* ps   = (const float*)d_in[23];
  const float* po   = (const float*)d_in[24];
  const float* ab   = (const float*)d_in[25];
  float* out = (float*)d_out;
  char* ws = (char*)d_ws;

  // P lives in d_out scratch (47.7 MB < 77 MB); fully consumed before k_proj
  // overwrites d_out with the real output.
  u16* Pbuf = (u16*)d_out;

  // ws layout — base ~104.8 MB; +XTg 50.3 MB (big); +Vg 117.4 MB (huge)
  float* bias2  = (float*)(ws + 0);          // 19208 f
  float* alpha  = (float*)(ws + 77056);      // 1536 f
  float* beta   = (float*)(ws + 83200);      // 1536 f
  float* alphap = (float*)(ws + 89344);      // 384 f
  float* betap  = (float*)(ws + 90880);      // 384 f
  u16*   Wqk16  = (u16*)(ws + 92416);        // [512][384]
  u16*   Wv16   = (u16*)(ws + 485632);       // [1024][384]
  u16*   Wp16   = (u16*)(ws + 1272064);      // [384][1024]
  u16*   Zs     = (u16*)(ws + 2058496);      // 1024 slabs of 50176 u16, Zt=[49][1024]
  bool big  = ws_size >= 155150592ull;       // base + XTg
  bool huge = ws_size >= 272591104ull;       // base + XTg + Vg
  u16*   XTg    = big  ? (u16*)(ws + 104818944) : (u16*)nullptr;  // [1024][64][384]
  u16*   Vg     = (u16*)(ws + 155150592);                          // [1024][1024][56]

  k_pre<<<3923, 256, 0, stream>>>(th1w, th1b, ab, qb, qs, qo, kb, ks, ko,
                                  vb, vs, vo, pb, ps, po, qw, kw, vw, pw,
                                  bias2, alpha, beta, alphap, betap,
                                  Wqk16, Wv16, Wp16);
  k_qk<<<1024, 512, 0, stream>>>(x, Wqk16, alpha, beta, Pbuf, XTg);
  k_mix<<<1024, 256, 0, stream>>>(Pbuf, bias2, th1w, th1b, th2w, th2b);
  if (huge) {
    k_vg<<<1024, 512, 0, stream>>>(XTg, Wv16, alpha, beta, Vg);
    k_pv<<<1024, 512, 0, stream>>>(Vg, vlw, vlb, vls, vlo, Pbuf, Zs);
  } else if (big) {
    k_av_x<<<1024, 512, 0, stream>>>(XTg, Wv16, alpha, beta, vlw, vlb, vls, vlo, Pbuf, Zs);
  } else {
    k_av_fb<<<1024, 512, 0, stream>>>(x, Wv16, alpha, beta, vlw, vlb, vls, vlo, Pbuf, Zs);
  }
  k_proj<<<1536, 512, 0, stream>>>(Wp16, Zs, alphap, betap, out);
}

// Round 6
// 540.610 us; speedup vs baseline: 2.4976x; 2.4976x over previous
//
#include <hip/hip_runtime.h>
#include <math.h>

typedef unsigned short u16;
typedef unsigned int u32;
typedef short short8 __attribute__((ext_vector_type(8)));
typedef float f32x4 __attribute__((ext_vector_type(4)));
typedef unsigned int u32x2 __attribute__((ext_vector_type(2)));

#define SCALE_QK 0.17677669529663687f  // 32^-0.5
#define PSLAB 23296                    // P slab per batch (u16): [8][52][56], lives in d_out

__device__ __forceinline__ float b2f(u16 v) { return __uint_as_float(((u32)v) << 16); }
__device__ __forceinline__ u16 f2b(float f) {
  u32 u = __float_as_uint(f);
  return (u16)((u + 0x7fffu + ((u >> 16) & 1u)) >> 16);
}

// Branchless GELU via A&S 7.1.26 erf (|eps| <= 1.5e-7): ~15 VALU, no divergence.
__device__ __forceinline__ float gelu_f(float z) {
  float y = z * 0.70710678118654752f;
  float a = fabsf(y);
  float t = __builtin_amdgcn_rcpf(fmaf(0.3275911f, a, 1.0f));
  float e = __expf(-y * y);
  float p = fmaf(1.061405429f, t, -1.453152027f);
  p = fmaf(p, t, 1.421413741f);
  p = fmaf(p, t, -0.284496736f);
  p = fmaf(p, t, 0.254829592f);
  p = p * t * e;                         // erfc(a) approx
  float phi = (y >= 0.f) ? fmaf(-0.5f, p, 1.0f) : 0.5f * p;
  return z * phi;
}

// ---- K0: fold BN params, premix bias through th1, convert weights to bf16 ----
__global__ __launch_bounds__(256) void k_pre(
    const float* __restrict__ th1w, const float* __restrict__ th1b, const float* __restrict__ ab,
    const float* __restrict__ qb, const float* __restrict__ qs, const float* __restrict__ qo,
    const float* __restrict__ kb, const float* __restrict__ ks, const float* __restrict__ ko,
    const float* __restrict__ vb, const float* __restrict__ vs, const float* __restrict__ vo,
    const float* __restrict__ pb, const float* __restrict__ ps, const float* __restrict__ po,
    const float* __restrict__ qw, const float* __restrict__ kw,
    const float* __restrict__ vw, const float* __restrict__ pw,
    float* __restrict__ bias2, float* __restrict__ alpha, float* __restrict__ beta,
    float* __restrict__ alphap, float* __restrict__ betap,
    u16* __restrict__ Wqk, u16* __restrict__ Wv, u16* __restrict__ Wp)
{
  int gid = blockIdx.x * 256 + threadIdx.x;
  if (gid < 19208) {
    int i = gid / 2401, rem = gid % 2401, n = rem / 49, m = rem % 49;
    int ry = abs(n / 7 - m / 7), rx = abs(n % 7 - m % 7);
    int idx = ry * 7 + rx;
    float acc = th1b[i];
    #pragma unroll
    for (int j = 0; j < 8; j++) acc += th1w[i * 8 + j] * ab[j * 49 + idx];
    bias2[gid] = acc;
  } else if (gid < 20744) {
    int c = gid - 19208;
    const float *s, *bb, *oo; int idx;
    if (c < 256)      { s = qs; bb = qb; oo = qo; idx = c; }
    else if (c < 512) { s = ks; bb = kb; oo = ko; idx = c - 256; }
    else              { s = vs; bb = vb; oo = vo; idx = c - 512; }
    float sv = s[idx];
    alpha[c] = sv;
    beta[c] = sv * bb[idx] + oo[idx];
  } else if (gid < 21128) {
    int c = gid - 20744;
    float sv = ps[c];
    alphap[c] = sv;
    betap[c] = sv * pb[c] + po[c];
  } else {
    int g = gid - 21128;
    if (g < 98304)       Wqk[g] = f2b(qw[g]);                 // q rows 0..255
    else if (g < 196608) Wqk[g] = f2b(kw[g - 98304]);         // k rows 256..511
    else if (g < 589824) Wv[g - 196608] = f2b(vw[g - 196608]);
    else if (g < 983040) Wp[g - 589824] = f2b(pw[g - 589824]);
  }
}

// ---- K1: per batch q/k GEMM + QK^T -> raw scaled scores into P (in d_out) ----
// Also exports the staged XT tile (bf16, [64][384], zero rows 49..63) to XTg
// when XTg != nullptr, so downstream kernels stage it back with no arithmetic.
__global__ __launch_bounds__(512, 4) void k_qk(
    const float* __restrict__ x, const u16* __restrict__ Wqk,
    const float* __restrict__ alpha, const float* __restrict__ beta,
    u16* __restrict__ Pbuf, u16* __restrict__ XTg)
{
  __shared__ __align__(16) u16 lds[37376];   // 74752 B -> 2 blocks/CU
  u16* XT = lds;               // [64][408]  (stride 816B: 16B-aligned)
  u16* Tq = lds + 26112;       // [64][88]
  u16* Tk = lds + 31744;       // [64][88]
  int t = threadIdx.x, wv = t >> 6, l = t & 63, quad = l >> 4, l16 = l & 15;
  int b = blockIdx.x;
  const float* xb = x + (size_t)b * 18816;

  for (int e = t; e < 18816; e += 512) {
    int k = e / 49, n = e - k * 49;
    XT[n * 408 + k] = f2b(xb[e]);
  }
  for (int e = t; e < 3060; e += 512) {  // zero rows 49..63 (must be finite!)
    int r = e / 204, kk = e - r * 204;
    ((u32*)(XT + (49 + r) * 408))[kk] = 0;
  }
  __syncthreads();

  if (XTg) {  // export XT (cols 0..383 only) to global; drains in background
    u32* dst = (u32*)(XTg + (size_t)b * 24576);
    const u32* src32 = (const u32*)XT;
    for (int e = t; e < 12288; e += 512) {
      int row = e / 192, cc = e - row * 192;
      dst[e] = src32[row * 204 + cc];
    }
  }

  u16* Pg = Pbuf + (size_t)b * PSLAB;   // [8][52][56]
  int isK = wv >= 4, wl = wv & 3;
  for (int hp = 0; hp < 4; hp++) {
    int cbase = (isK ? 256 : 0) + hp * 64 + wl * 16;
    f32x4 acc[4] = {};
    const u16* Wr = Wqk + (size_t)(cbase + l16) * 384;
    short8 afr[12];                        // preload A frags: one latency, not 12
    #pragma unroll
    for (int ks = 0; ks < 12; ks++) afr[ks] = *(const short8*)(Wr + ks * 32 + quad * 8);
    #pragma unroll
    for (int ks = 0; ks < 12; ks++) {
      #pragma unroll
      for (int nt = 0; nt < 4; nt++) {
        short8 bf = *(const short8*)(&XT[(nt * 16 + l16) * 408 + ks * 32 + quad * 8]);
        acc[nt] = __builtin_amdgcn_mfma_f32_16x16x32_bf16(afr[ks], bf, acc[nt], 0, 0, 0);
      }
    }
    u16* Tdst = isK ? Tk : Tq;
    #pragma unroll
    for (int reg = 0; reg < 4; reg++) {
      int c = cbase + quad * 4 + reg;
      float al = alpha[c], be = beta[c];
      int cl = wl * 16 + quad * 4 + reg;
      #pragma unroll
      for (int nt = 0; nt < 4; nt++)
        Tdst[(nt * 16 + l16) * 88 + cl] = f2b(acc[nt][reg] * al + be);
    }
    __syncthreads();
    #pragma unroll
    for (int ui = 0; ui < 4; ui++) {
      int u = wv * 4 + ui;                    // 32 tiles: 2 heads x 4x4
      int hl = u >> 4, tn = (u >> 2) & 3, tm = u & 3;
      short8 a  = *(const short8*)(&Tq[(tn * 16 + l16) * 88 + hl * 32 + quad * 8]);
      short8 bb = *(const short8*)(&Tk[(tm * 16 + l16) * 88 + hl * 32 + quad * 8]);
      f32x4 c = {};
      c = __builtin_amdgcn_mfma_f32_16x16x32_bf16(a, bb, c, 0, 0, 0);
      int h = hp * 2 + hl;
      #pragma unroll
      for (int r = 0; r < 4; r++) {
        int n = tn * 16 + quad * 4 + r, m = tm * 16 + l16;
        // write full padded slab: pads = 0 (d_out is poisoned; no NaN may survive)
        if (n < 52 && m < 56)
          Pg[(h * 52 + n) * 56 + m] = (n < 49 && m < 49) ? f2b(c[r] * SCALE_QK) : (u16)0;
      }
    }
    __syncthreads();
  }
}

// ---- K2: mix1 + bias, softmax, mix2 — in place on P ----
__global__ __launch_bounds__(256, 4) void k_mix(
    u16* __restrict__ Pbuf, const float* __restrict__ bias2,
    const float* __restrict__ th1w, const float* __restrict__ th1b,
    const float* __restrict__ th2w, const float* __restrict__ th2b)
{
  __shared__ u16 SB[23296];    // [8][52][56]
  __shared__ float TH[144];
  int t = threadIdx.x, b = blockIdx.x;
  u32* Pg32 = (u32*)(Pbuf + (size_t)b * PSLAB);
  for (int e = t; e < 11648; e += 256) ((u32*)SB)[e] = Pg32[e];
  if (t < 64)       TH[t] = th1w[t];
  else if (t < 72)  TH[t] = th1b[t - 64];
  else if (t < 136) TH[t] = th2w[t - 72];
  else if (t < 144) TH[t] = th2b[t - 136];
  __syncthreads();
  for (int e = t; e < 2401; e += 256) {
    int n = e / 49, m = e - n * 49;
    float s[8], uo[8];
    #pragma unroll
    for (int j = 0; j < 8; j++) s[j] = b2f(SB[(j * 52 + n) * 56 + m]);
    #pragma unroll
    for (int i = 0; i < 8; i++) {
      float a2 = bias2[(i * 49 + n) * 49 + m];
      #pragma unroll
      for (int j = 0; j < 8; j++) a2 += TH[i * 8 + j] * s[j];
      uo[i] = a2;
    }
    #pragma unroll
    for (int i = 0; i < 8; i++) SB[(i * 52 + n) * 56 + m] = f2b(uo[i]);
  }
  __syncthreads();
  for (int r0 = t; r0 < 392; r0 += 256) {
    int i = r0 / 49, n = r0 - i * 49;
    u16* row = &SB[(i * 52 + n) * 56];
    float v[49]; float mx = -1e30f;
    #pragma unroll
    for (int m = 0; m < 49; m++) { v[m] = b2f(row[m]); mx = fmaxf(mx, v[m]); }
    float sum = 0.f;
    #pragma unroll
    for (int m = 0; m < 49; m++) { v[m] = __expf(v[m] - mx); sum += v[m]; }
    float inv = 1.f / sum;
    #pragma unroll
    for (int m = 0; m < 49; m++) row[m] = f2b(v[m] * inv);
  }
  __syncthreads();
  for (int e = t; e < 2401; e += 256) {
    int n = e / 49, m = e - n * 49;
    float s[8], uo[8];
    #pragma unroll
    for (int j = 0; j < 8; j++) s[j] = b2f(SB[(j * 52 + n) * 56 + m]);
    #pragma unroll
    for (int i = 0; i < 8; i++) {
      float a2 = TH[136 + i];
      #pragma unroll
      for (int j = 0; j < 8; j++) a2 += TH[72 + i * 8 + j] * s[j];
      uo[i] = a2;
    }
    #pragma unroll
    for (int i = 0; i < 8; i++) SB[(i * 52 + n) * 56 + m] = f2b(uo[i]);
  }
  __syncthreads();
  for (int e = t; e < 11648; e += 256) Pg32[e] = ((u32*)SB)[e];
}

// ---- K3 (big-ws): monolithic v-GEMM + PV + dwconv + GELU, 1 barrier/head.
// VT is wave-private (wave wv writes AND reads only rows wv*16..+15), so the
// only cross-wave LDS object is the 5.7KB P tile -> double-buffer it: loads
// for head h+1 issue before the GEMM (latency hidden), land in the alternate
// buffer, and the single end-of-head barrier publishes them. Waves drift
// within a head: epilogue VALU of one wave overlaps GEMM MFMA of another.
// XT stride 392 (vs 408) keeps LDS at 81600 B <= 81920 -> 2 blocks/CU.
__global__ __launch_bounds__(512, 4) void k_av_x(
    const u16* __restrict__ XTg, const u16* __restrict__ Wv,
    const float* __restrict__ alpha, const float* __restrict__ beta,
    const float* __restrict__ vlw, const float* __restrict__ vlb,
    const float* __restrict__ vls, const float* __restrict__ vlo,
    const u16* __restrict__ Pbuf, u16* __restrict__ Zs)
{
  __shared__ __align__(16) u16 lds[40800];   // 81600 B
  u16* XT  = lds;                // [64][392], data cols 0..383
  u16* VT  = lds + 25088;        // [128][72], data at col 8+m; pads stay zero
  u16* Ph0 = lds + 34304;        // [52][56]
  u16* Ph1 = lds + 37216;        // [52][56] (reads past row 51 hit tail, discarded)
  int t = threadIdx.x, wv = t >> 6, l = t & 63, quad = l >> 4, l16 = l & 15;
  int b = blockIdx.x;

  { // XT import: zero-arithmetic restage of k_qk's exported tile
    const short8* src8 = (const short8*)(XTg + (size_t)b * 24576);
    for (int e = t; e < 3072; e += 512) {
      int row = e / 48, cc = e - row * 48;
      *(short8*)(XT + row * 392 + cc * 8) = src8[e];
    }
  }
  { // wave-private VT pad zero: own 16 rows, cols {0..7, 56..63, 64..71}
    int row = wv * 16 + (l >> 2), k2 = (l & 3) * 2;
    *(u32*)(&VT[row * 72 + k2]) = 0;
    *(u32*)(&VT[row * 72 + 56 + k2]) = 0;
    *(u32*)(&VT[row * 72 + 64 + k2]) = 0;
  }
  const u16* Pgb = Pbuf + (size_t)b * PSLAB;
  { // prologue: Ph0 <- P tile of head 0
    const u32* src = (const u32*)Pgb;
    for (int e = t; e < 1456; e += 512) ((u32*)Ph0)[e] = src[e];
  }
  __syncthreads();

  u16* Zb = Zs + (size_t)b * 50176;          // Zt: [49][1024], n-major
  int d = wv * 16 + l16;
  for (int h = 0; h < 8; h++) {
    u16* PhR = (h & 1) ? Ph1 : Ph0;
    u16* PhW = (h & 1) ? Ph0 : Ph1;
    // issue next head's P loads now; they land after the GEMM
    u32 pr0 = 0, pr1 = 0, pr2 = 0;
    if (h < 7) {
      const u32* src = (const u32*)(Pgb + (h + 1) * 2912);
      pr0 = src[t]; pr1 = src[t + 512];
      if (t < 432) pr2 = src[t + 1024];
    }
    int c = h * 128 + d;
    const u16* Wr = Wv + (size_t)c * 384;
    short8 afr[12];
    #pragma unroll
    for (int ks = 0; ks < 12; ks++) afr[ks] = *(const short8*)(Wr + ks * 32 + quad * 8);
    float w9[9];
    #pragma unroll
    for (int j = 0; j < 9; j++) w9[j] = vlw[c * 9 + j];
    float sv = vls[c];
    float cb = sv * vlb[c] + vlo[c];

    f32x4 va[4] = {};
    #pragma unroll
    for (int ks = 0; ks < 12; ks++) {
      #pragma unroll
      for (int nt = 0; nt < 4; nt++) {
        short8 bf = *(const short8*)(&XT[(nt * 16 + l16) * 392 + ks * 32 + quad * 8]);
        va[nt] = __builtin_amdgcn_mfma_f32_16x16x32_bf16(afr[ks], bf, va[nt], 0, 0, 0);
      }
    }
    // VT write (wave-private rows)
    #pragma unroll
    for (int reg = 0; reg < 4; reg++) {
      int dl = wv * 16 + quad * 4 + reg;
      int cc = h * 128 + dl;
      float al = alpha[512 + cc], be = beta[512 + cc];
      #pragma unroll
      for (int nt = 0; nt < 4; nt++) {
        int m = nt * 16 + l16;
        if (m < 49) VT[dl * 72 + 8 + m] = f2b(va[nt][reg] * al + be);
      }
    }
    // park staged P into the write buffer (published by the barrier below)
    if (h < 7) {
      u32* dst = (u32*)PhW;
      dst[t] = pr0; dst[t + 512] = pr1;
      if (t < 432) dst[t + 1024] = pr2;
    }
    asm volatile("" ::: "memory");   // keep VT writes ordered before reads below
    // PV: reads PhR (published last barrier) + own VT rows
    f32x4 oa[4] = {};
    #pragma unroll
    for (int ks2 = 0; ks2 < 2; ks2++) {
      int mb = ks2 * 32 + quad * 8;
      short8 bf = *(const short8*)(&VT[(wv * 16 + l16) * 72 + 8 + mb]);
      #pragma unroll
      for (int tn = 0; tn < 4; tn++) {
        short8 af = *(const short8*)(&PhR[(tn * 16 + l16) * 56 + mb]);
        oa[tn] = __builtin_amdgcn_mfma_f32_16x16x32_bf16(af, bf, oa[tn], 0, 0, 0);
      }
    }
    // dwconv + GELU + transposed Z store
    const u16* vtr = &VT[d * 72];
    #pragma unroll
    for (int tn = 0; tn < 4; tn++) {
      int n0 = tn * 16 + quad * 4;
      const u16* vr = vtr + n0;      // col(n0+j) holds spatial m = n0+j-8
      float q[20];
      #pragma unroll
      for (int jj = 0; jj < 5; jj++) {
        u32x2 U = *(const u32x2*)(vr + jj * 4);
        q[jj * 4 + 0] = __uint_as_float(U.x << 16);
        q[jj * 4 + 1] = __uint_as_float(U.x & 0xffff0000u);
        q[jj * 4 + 2] = __uint_as_float(U.y << 16);
        q[jj * 4 + 3] = __uint_as_float(U.y & 0xffff0000u);
      }
      #pragma unroll
      for (int r = 0; r < 4; r++) {
        int n = n0 + r;
        int yi = (n * 37) >> 8;        // == n/7 for n < 64
        int xi = n - yi * 7;
        bool xl = xi > 0, xr = xi < 6;
        float w0m = xl ? w9[0] : 0.f, w3m = xl ? w9[3] : 0.f, w6m = xl ? w9[6] : 0.f;
        float w2m = xr ? w9[2] : 0.f, w5m = xr ? w9[5] : 0.f, w8m = xr ? w9[8] : 0.f;
        float conv = q[r]      * w0m + q[r + 1]  * w9[1] + q[r + 2]  * w2m
                   + q[r + 7]  * w3m + q[r + 8]  * w9[4] + q[r + 9]  * w5m
                   + q[r + 14] * w6m + q[r + 15] * w9[7] + q[r + 16] * w8m;
        float z = oa[tn][r] + conv * sv + cb;
        float g = gelu_f(z);
        if (n < 49) Zb[(size_t)n * 1024 + c] = f2b(g);
      }
    }
    __syncthreads();   // publishes PhW for head h+1; VT needs no cross-wave sync
  }
}

// ---- K3 (small-ws fallback): round-2 k_av, stages from x directly ----
__global__ __launch_bounds__(512, 4) void k_av_fb(
    const float* __restrict__ x, const u16* __restrict__ Wv,
    const float* __restrict__ alpha, const float* __restrict__ beta,
    const float* __restrict__ vlw, const float* __restrict__ vlb,
    const float* __restrict__ vls, const float* __restrict__ vlo,
    const u16* __restrict__ Pbuf, u16* __restrict__ Zs)
{
  __shared__ __align__(16) u16 lds[38968];
  u16* XT = lds;               // [64][408]
  u16* VT = lds + 26112;       // [128][72]
  u16* Ph = lds + 35328;       // [65][56]
  int t = threadIdx.x, wv = t >> 6, l = t & 63, quad = l >> 4, l16 = l & 15;
  int b = blockIdx.x;
  const float* xb = x + (size_t)b * 18816;

  for (int e = t; e < 18816; e += 512) {
    int k = e / 49, n = e - k * 49;
    XT[n * 408 + k] = f2b(xb[e]);
  }
  for (int e = t; e < 3060; e += 512) {
    int r = e / 204, kk = e - r * 204;
    ((u32*)(XT + (49 + r) * 408))[kk] = 0;
  }
  for (int e = t; e < 4608; e += 512) ((u32*)VT)[e] = 0;
  __syncthreads();

  u16* Zb = Zs + (size_t)b * 50176;
  const u16* Pgb = Pbuf + (size_t)b * PSLAB;
  for (int h = 0; h < 8; h++) {
    {
      const u32* src = (const u32*)(Pgb + h * 2912);
      for (int e = t; e < 1456; e += 512) ((u32*)Ph)[e] = src[e];
    }
    const u16* Wr = Wv + (size_t)(h * 128 + wv * 16 + l16) * 384;
    short8 afr[12];
    #pragma unroll
    for (int ks = 0; ks < 12; ks++) afr[ks] = *(const short8*)(Wr + ks * 32 + quad * 8);
    int d = wv * 16 + l16, c = h * 128 + d;
    float w9[9];
    #pragma unroll
    for (int j = 0; j < 9; j++) w9[j] = vlw[c * 9 + j];
    float sv = vls[c];
    float cb = sv * vlb[c] + vlo[c];

    f32x4 va[4] = {};
    #pragma unroll
    for (int ks = 0; ks < 12; ks++) {
      #pragma unroll
      for (int nt = 0; nt < 4; nt++) {
        short8 bf = *(const short8*)(&XT[(nt * 16 + l16) * 408 + ks * 32 + quad * 8]);
        va[nt] = __builtin_amdgcn_mfma_f32_16x16x32_bf16(afr[ks], bf, va[nt], 0, 0, 0);
      }
    }
    #pragma unroll
    for (int reg = 0; reg < 4; reg++) {
      int dl = wv * 16 + quad * 4 + reg;
      int cc = h * 128 + dl;
      float al = alpha[512 + cc], be = beta[512 + cc];
      #pragma unroll
      for (int nt = 0; nt < 4; nt++) {
        int m = nt * 16 + l16;
        if (m < 49) VT[dl * 72 + 8 + m] = f2b(va[nt][reg] * al + be);
      }
    }
    __syncthreads();
    f32x4 oa[4] = {};
    #pragma unroll
    for (int ks2 = 0; ks2 < 2; ks2++) {
      int mb = ks2 * 32 + quad * 8;
      short8 bf = *(const short8*)(&VT[(wv * 16 + l16) * 72 + 8 + mb]);
      #pragma unroll
      for (int tn = 0; tn < 4; tn++) {
        short8 af = *(const short8*)(&Ph[(tn * 16 + l16) * 56 + mb]);
        oa[tn] = __builtin_amdgcn_mfma_f32_16x16x32_bf16(af, bf, oa[tn], 0, 0, 0);
      }
    }
    const u16* vtr = &VT[d * 72];
    #pragma unroll
    for (int tn = 0; tn < 4; tn++) {
      int n0 = tn * 16 + quad * 4;
      const u16* vr = vtr + n0;
      float q[20];
      #pragma unroll
      for (int jj = 0; jj < 5; jj++) {
        u32x2 U = *(const u32x2*)(vr + jj * 4);
        q[jj * 4 + 0] = __uint_as_float(U.x << 16);
        q[jj * 4 + 1] = __uint_as_float(U.x & 0xffff0000u);
        q[jj * 4 + 2] = __uint_as_float(U.y << 16);
        q[jj * 4 + 3] = __uint_as_float(U.y & 0xffff0000u);
      }
      #pragma unroll
      for (int r = 0; r < 4; r++) {
        int n = n0 + r;
        int yi = (n * 37) >> 8;
        int xi = n - yi * 7;
        bool xl = xi > 0, xr = xi < 6;
        float w0m = xl ? w9[0] : 0.f, w3m = xl ? w9[3] : 0.f, w6m = xl ? w9[6] : 0.f;
        float w2m = xr ? w9[2] : 0.f, w5m = xr ? w9[5] : 0.f, w8m = xr ? w9[8] : 0.f;
        float conv = q[r]      * w0m + q[r + 1]  * w9[1] + q[r + 2]  * w2m
                   + q[r + 7]  * w3m + q[r + 8]  * w9[4] + q[r + 9]  * w5m
                   + q[r + 14] * w6m + q[r + 15] * w9[7] + q[r + 16] * w8m;
        float z = oa[tn][r] + conv * sv + cb;
        float g = gelu_f(z);
        if (n < 49) Zb[(size_t)n * 1024 + c] = f2b(g);
      }
    }
    __syncthreads();
  }
}

// ---- K4: output projection, 128x128 tiles, 2 batches/block ----
__global__ __launch_bounds__(512, 4) void k_proj(
    const u16* __restrict__ Wp, const u16* __restrict__ Zt,
    const float* __restrict__ alphap, const float* __restrict__ betap,
    float* __restrict__ out)
{
  __shared__ __align__(16) u16 Bs[128 * 152];   // 38912 B -> 4 blocks/CU
  int t = threadIdx.x, wv = t >> 6, l = t & 63, quad = l >> 4, l16 = l & 15;
  int g = blockIdx.x;
  int vb = (g & 7) * 192 + (g >> 3);
  int mb = vb % 3;
  size_t b0 = (size_t)(vb / 3) * 2;
  f32x4 acc[8] = {};
  const u16* Wr = Wp + (size_t)(mb * 128 + wv * 16 + l16) * 1024;
  for (int k0 = 0; k0 < 1024; k0 += 128) {
    #pragma unroll
    for (int i = 0; i < 4; i++) {
      int ch = t + i * 512;              // 2048 chunks of 8 u16
      int np = ch >> 4, ck = ch & 15;
      int pb = np >> 6, n = np & 63;
      short8 v = {};
      if (n < 49)
        v = *(const short8*)(Zt + (b0 + pb) * 50176 + (size_t)n * 1024 + k0 + ck * 8);
      *(short8*)(&Bs[np * 152 + ck * 8]) = v;
    }
    __syncthreads();
    #pragma unroll
    for (int ksi = 0; ksi < 4; ksi++) {
      short8 af = *(const short8*)(Wr + k0 + ksi * 32 + quad * 8);
      #pragma unroll
      for (int nt = 0; nt < 8; nt++) {
        short8 bf = *(const short8*)(&Bs[(nt * 16 + l16) * 152 + ksi * 32 + quad * 8]);
        acc[nt] = __builtin_amdgcn_mfma_f32_16x16x32_bf16(af, bf, acc[nt], 0, 0, 0);
      }
    }
    __syncthreads();
  }
  #pragma unroll
  for (int reg = 0; reg < 4; reg++) {
    int c = mb * 128 + wv * 16 + quad * 4 + reg;
    float al = alphap[c], be = betap[c];
    #pragma unroll
    for (int nt = 0; nt < 8; nt++) {
      int np = nt * 16 + l16, pb = np >> 6, n = np & 63;
      if (n < 49) out[(b0 + pb) * 18816 + (size_t)c * 49 + n] = acc[nt][reg] * al + be;
    }
  }
}

extern "C" void kernel_launch(void* const* d_in, const int* in_sizes, int n_in,
                              void* d_out, int out_size, void* d_ws, size_t ws_size,
                              hipStream_t stream) {
  const float* x    = (const float*)d_in[0];
  const float* qw   = (const float*)d_in[1];
  const float* qb   = (const float*)d_in[2];
  const float* qs   = (const float*)d_in[3];
  const float* qo   = (const float*)d_in[4];
  const float* kw   = (const float*)d_in[5];
  const float* kb   = (const float*)d_in[6];
  const float* ks   = (const float*)d_in[7];
  const float* ko   = (const float*)d_in[8];
  const float* vw   = (const float*)d_in[9];
  const float* vb   = (const float*)d_in[10];
  const float* vs   = (const float*)d_in[11];
  const float* vo   = (const float*)d_in[12];
  const float* vlw  = (const float*)d_in[13];
  const float* vlb  = (const float*)d_in[14];
  const float* vls  = (const float*)d_in[15];
  const float* vlo  = (const float*)d_in[16];
  const float* th1w = (const float*)d_in[17];
  const float* th1b = (const float*)d_in[18];
  const float* th2w = (const float*)d_in[19];
  const float* th2b = (const float*)d_in[20];
  const float* pw   = (const float*)d_in[21];
  const float* pb   = (const float*)d_in[22];
  const float* ps   = (const float*)d_in[23];
  const float* po   = (const float*)d_in[24];
  const float* ab   = (const float*)d_in[25];
  float* out = (float*)d_out;
  char* ws = (char*)d_ws;

  // P lives in d_out scratch (47.7 MB < 77 MB); fully consumed before k_proj
  // overwrites d_out with the real output.
  u16* Pbuf = (u16*)d_out;

  // ws layout — base ~104.8 MB; +XTg 50.3 MB (big)
  float* bias2  = (float*)(ws + 0);          // 19208 f
  float* alpha  = (float*)(ws + 77056);      // 1536 f
  float* beta   = (float*)(ws + 83200);      // 1536 f
  float* alphap = (float*)(ws + 89344);      // 384 f
  float* betap  = (float*)(ws + 90880);      // 384 f
  u16*   Wqk16  = (u16*)(ws + 92416);        // [512][384]
  u16*   Wv16   = (u16*)(ws + 485632);       // [1024][384]
  u16*   Wp16   = (u16*)(ws + 1272064);      // [384][1024]
  u16*   Zs     = (u16*)(ws + 2058496);      // 1024 slabs of 50176 u16, Zt=[49][1024]
  bool big = ws_size >= 155150592ull;        // base + XTg
  u16*   XTg    = big ? (u16*)(ws + 104818944) : (u16*)nullptr;  // [1024][64][384]

  k_pre<<<3923, 256, 0, stream>>>(th1w, th1b, ab, qb, qs, qo, kb, ks, ko,
                                  vb, vs, vo, pb, ps, po, qw, kw, vw, pw,
                                  bias2, alpha, beta, alphap, betap,
                                  Wqk16, Wv16, Wp16);
  k_qk<<<1024, 512, 0, stream>>>(x, Wqk16, alpha, beta, Pbuf, XTg);
  k_mix<<<1024, 256, 0, stream>>>(Pbuf, bias2, th1w, th1b, th2w, th2b);
  if (big)
    k_av_x<<<1024, 512, 0, stream>>>(XTg, Wv16, alpha, beta, vlw, vlb, vls, vlo, Pbuf, Zs);
  else
    k_av_fb<<<1024, 512, 0, stream>>>(x, Wv16, alpha, beta, vlw, vlb, vls, vlo, Pbuf, Zs);
  k_proj<<<1536, 512, 0, stream>>>(Wp16, Zs, alphap, betap, out);
}